// Round 1
// baseline (1071.550 us; speedup 1.0000x reference)
//
#include <hip/hip_runtime.h>
#include <math.h>

// AnswerPointerNetwork: H=256, B=64, LP=2048, LQ=64, all fp32.
// Decomposition:
//   v2 = WQv@VQr+b                                   (tiny)
//   G1 = quesEnc@WQu^T + WQu_b                       (GEMM M=4096 K=512 N=256)
//   sQ/softmax/rQ fused per-batch                    (64 blocks)
//   u1 = rQ@Wah^T + Wah_b                            (GEMM M=64)
//   passP = passEnc@WPh^T + WPh_b                    (GEMM M=131072 — dominant, 34.4 GF fp32)
//   sP1 = sum_h tanh(passP+u1)*Vt2 ; softmax -> aP1  (memory-bound over passP)
//   ct = sum_p aP1*passEnc                           (memory-bound over passEnc, atomics)
//   GRU: gi=rQ@wih^T+bih, gh=ct@whh^T+bhh, gates     (GEMMs M=64 N=1536)
//   u2 = rQ2@Wah^T ; sP2 ; softmax -> aP2

constexpr int Bn   = 64;
constexpr int Hn   = 256;
constexpr int D2H  = 512;
constexpr int LPn  = 2048;
constexpr int LQn  = 64;

__device__ inline float waveAllSum(float v) {
  #pragma unroll
  for (int o = 32; o > 0; o >>= 1) v += __shfl_xor(v, o, 64);
  return v;
}
__device__ inline float waveAllMax(float v) {
  #pragma unroll
  for (int o = 32; o > 0; o >>= 1) v = fmaxf(v, __shfl_xor(v, o, 64));
  return v;
}

// ---------------- tiny: v2 = VQr @ WQv_W.T + WQv_b ----------------
__global__ __launch_bounds__(256) void k_v2(const float* __restrict__ VQr,
                                            const float* __restrict__ WQv_W,
                                            const float* __restrict__ WQv_b,
                                            float* __restrict__ v2) {
  __shared__ float s[256];
  int t = threadIdx.x;
  s[t] = VQr[t];
  __syncthreads();
  float acc = WQv_b[t];
  for (int k = 0; k < 256; ++k) acc += s[k] * WQv_W[t * 256 + k];
  v2[t] = acc;
}

// ---------------- generic fp32 GEMM: C[M][N] = A[M][K] @ W[N][K]^T + bias[N] ----
// block tile 64x64, thread 4x4, TK=32. M%64==0, N%64==0, K%32==0.
constexpr int TM = 64, TN = 64, TK = 32;
constexpr int PAD = 4;  // keeps k-row stride = 68 floats = 272B (16B aligned) for ds_read_b128

__global__ __launch_bounds__(256) void k_gemm(const float* __restrict__ A,
                                              const float* __restrict__ W,
                                              const float* __restrict__ bias,
                                              float* __restrict__ C,
                                              int M, int N, int K) {
  __shared__ float As[TK][TM + PAD];
  __shared__ float Bs[TK][TN + PAD];
  const int bm = blockIdx.x * TM;
  const int bn = blockIdx.y * TN;
  const int tid = threadIdx.x;
  const int tx = tid & 15;  // 0..15 -> cols
  const int ty = tid >> 4;  // 0..15 -> rows
  float acc[4][4] = {};

  for (int k0 = 0; k0 < K; k0 += TK) {
    #pragma unroll
    for (int i = 0; i < 2; ++i) {
      int f = tid + 256 * i;       // 0..511 float4 slots
      int m = f >> 3;              // 0..63
      int kq = (f & 7) << 2;       // 0,4,...,28
      float4 v = *(const float4*)&A[(size_t)(bm + m) * K + k0 + kq];
      As[kq + 0][m] = v.x; As[kq + 1][m] = v.y; As[kq + 2][m] = v.z; As[kq + 3][m] = v.w;
    }
    #pragma unroll
    for (int i = 0; i < 2; ++i) {
      int f = tid + 256 * i;
      int n = f >> 3;
      int kq = (f & 7) << 2;
      float4 v = *(const float4*)&W[(size_t)(bn + n) * K + k0 + kq];
      Bs[kq + 0][n] = v.x; Bs[kq + 1][n] = v.y; Bs[kq + 2][n] = v.z; Bs[kq + 3][n] = v.w;
    }
    __syncthreads();
    #pragma unroll
    for (int k = 0; k < TK; ++k) {
      float4 a4 = *(const float4*)&As[k][ty * 4];
      float4 b4 = *(const float4*)&Bs[k][tx * 4];
      float aa[4] = {a4.x, a4.y, a4.z, a4.w};
      float bb[4] = {b4.x, b4.y, b4.z, b4.w};
      #pragma unroll
      for (int i = 0; i < 4; ++i)
        #pragma unroll
        for (int j = 0; j < 4; ++j)
          acc[i][j] = fmaf(aa[i], bb[j], acc[i][j]);
    }
    __syncthreads();
  }

  float4 bset = *(const float4*)&bias[bn + tx * 4];
  #pragma unroll
  for (int i = 0; i < 4; ++i) {
    int m = bm + ty * 4 + i;
    float4 v;
    v.x = acc[i][0] + bset.x;
    v.y = acc[i][1] + bset.y;
    v.z = acc[i][2] + bset.z;
    v.w = acc[i][3] + bset.w;
    *(float4*)&C[(size_t)m * N + bn + tx * 4] = v;
  }
}

// ---------------- sQ -> softmax -> rQ, one block per b ----------------
__global__ __launch_bounds__(256) void k_sq_rq(const float* __restrict__ G1,
                                               const float* __restrict__ v2,
                                               const float* __restrict__ Vt1,
                                               const float* __restrict__ quesEnc,
                                               float* __restrict__ rQ) {
  int b = blockIdx.x, tid = threadIdx.x;
  int lane = tid & 63, wid = tid >> 6;
  __shared__ float s_a[LQn];
  __shared__ float red[4];
  float v2h = v2[tid];
  float vt = Vt1[b * Hn + tid];
  for (int q = 0; q < LQn; ++q) {
    float g = G1[(size_t)(q * Bn + b) * Hn + tid];
    float val = tanhf(g + v2h) * vt;
    float wsum = waveAllSum(val);
    if (lane == 0) red[wid] = wsum;
    __syncthreads();
    if (tid == 0) s_a[q] = red[0] + red[1] + red[2] + red[3];
    __syncthreads();
  }
  if (tid < 64) {
    float s = s_a[tid];
    float m = waveAllMax(s);
    float e = expf(s - m);
    float sum = waveAllSum(e);
    s_a[tid] = e / sum;
  }
  __syncthreads();
  #pragma unroll
  for (int rep = 0; rep < 2; ++rep) {
    int d = tid + rep * 256;
    float acc = 0.f;
    for (int q = 0; q < LQn; ++q)
      acc += s_a[q] * quesEnc[(size_t)(q * Bn + b) * D2H + d];
    rQ[b * D2H + d] = acc;
  }
}

// ---------------- sP[b][p] = sum_h tanh(passP[p,b,h]+u[b,h])*Vt2[b,h] ------
// one wave per (p,b) row; 4 waves/block.
__global__ __launch_bounds__(256) void k_sp(const float* __restrict__ passP,
                                            const float* __restrict__ u,
                                            const float* __restrict__ Vt2,
                                            float* __restrict__ sP) {
  int flat = blockIdx.x * 4 + (threadIdx.x >> 6);  // = p*B + b
  int lane = threadIdx.x & 63;
  int b = flat & (Bn - 1);
  int p = flat >> 6;
  float4 v  = *(const float4*)&passP[(size_t)flat * Hn + lane * 4];
  float4 uu = *(const float4*)&u[b * Hn + lane * 4];
  float4 vt = *(const float4*)&Vt2[b * Hn + lane * 4];
  float s = tanhf(v.x + uu.x) * vt.x + tanhf(v.y + uu.y) * vt.y +
            tanhf(v.z + uu.z) * vt.z + tanhf(v.w + uu.w) * vt.w;
  s = waveAllSum(s);
  if (lane == 0) sP[b * LPn + p] = s;
}

// ---------------- softmax over 2048, one block per b ----------------
__global__ __launch_bounds__(256) void k_softmax(const float* __restrict__ sP,
                                                 float* __restrict__ out) {
  int b = blockIdx.x, tid = threadIdx.x;
  int lane = tid & 63, wid = tid >> 6;
  __shared__ float red[4];
  float v[8];
  float m = -1e30f;
  #pragma unroll
  for (int i = 0; i < 8; ++i) {
    v[i] = sP[b * LPn + i * 256 + tid];
    m = fmaxf(m, v[i]);
  }
  m = waveAllMax(m);
  if (lane == 0) red[wid] = m;
  __syncthreads();
  m = fmaxf(fmaxf(red[0], red[1]), fmaxf(red[2], red[3]));
  float s = 0.f;
  #pragma unroll
  for (int i = 0; i < 8; ++i) { v[i] = expf(v[i] - m); s += v[i]; }
  s = waveAllSum(s);
  __syncthreads();
  if (lane == 0) red[wid] = s;
  __syncthreads();
  s = red[0] + red[1] + red[2] + red[3];
  float inv = 1.0f / s;
  #pragma unroll
  for (int i = 0; i < 8; ++i) out[b * LPn + i * 256 + tid] = v[i] * inv;
}

// ---------------- ct[b][d] = sum_p aP[b][p]*passEnc[p,b,d] ----------------
// grid (64 b, 32 p-chunks), fp32 atomics into zeroed ct.
__global__ __launch_bounds__(256) void k_ct(const float* __restrict__ aP,
                                            const float* __restrict__ passEnc,
                                            float* __restrict__ ct) {
  int b = blockIdx.x;
  int p0 = blockIdx.y * 64;
  int tid = threadIdx.x;
  float acc0 = 0.f, acc1 = 0.f;
  for (int pp = 0; pp < 64; ++pp) {
    int p = p0 + pp;
    float a = aP[b * LPn + p];
    const float* row = &passEnc[(size_t)(p * Bn + b) * D2H];
    acc0 += a * row[tid];
    acc1 += a * row[tid + 256];
  }
  atomicAdd(&ct[b * D2H + tid], acc0);
  atomicAdd(&ct[b * D2H + tid + 256], acc1);
}

// ---------------- GRU gates ----------------
__global__ __launch_bounds__(256) void k_gates(const float* __restrict__ gi,
                                               const float* __restrict__ gh,
                                               const float* __restrict__ ct,
                                               float* __restrict__ rQ2) {
  int idx = blockIdx.x * 256 + threadIdx.x;  // 0..32767
  int b = idx >> 9;
  int j = idx & 511;
  const float* gib = gi + b * 1536;
  const float* ghb = gh + b * 1536;
  float r = 1.f / (1.f + expf(-(gib[j] + ghb[j])));
  float z = 1.f / (1.f + expf(-(gib[512 + j] + ghb[512 + j])));
  float n = tanhf(gib[1024 + j] + r * ghb[1024 + j]);
  rQ2[b * D2H + j] = (1.f - z) * n + z * ct[b * D2H + j];
}

extern "C" void kernel_launch(void* const* d_in, const int* in_sizes, int n_in,
                              void* d_out, int out_size, void* d_ws, size_t ws_size,
                              hipStream_t stream) {
  const float* passEnc  = (const float*)d_in[0];
  const float* quesEnc  = (const float*)d_in[1];
  const float* WQu_W    = (const float*)d_in[2];
  const float* WQu_b    = (const float*)d_in[3];
  const float* WQv_W    = (const float*)d_in[4];
  const float* WQv_b    = (const float*)d_in[5];
  const float* WPh_W    = (const float*)d_in[6];
  const float* WPh_b    = (const float*)d_in[7];
  const float* Wah_W    = (const float*)d_in[8];
  const float* Wah_b    = (const float*)d_in[9];
  const float* Vt1      = (const float*)d_in[10];
  const float* Vt2      = (const float*)d_in[11];
  const float* VQr      = (const float*)d_in[12];
  const float* gru_wih  = (const float*)d_in[13];
  const float* gru_whh  = (const float*)d_in[14];
  const float* gru_bih  = (const float*)d_in[15];
  const float* gru_bhh  = (const float*)d_in[16];
  float* out = (float*)d_out;

  // workspace layout (floats)
  float* ws = (float*)d_ws;
  float* passP = ws;                         // 33554432
  float* G1    = ws + 33554432;              // 1048576
  float* v2    = G1 + 1048576;               // 256
  float* rQ    = v2 + 256;                   // 32768
  float* u1    = rQ + 32768;                 // 16384
  float* u2    = u1 + 16384;                 // 16384
  float* sP    = u2 + 16384;                 // 131072
  float* ct    = sP + 131072;                // 32768
  float* gi    = ct + 32768;                 // 98304
  float* gh    = gi + 98304;                 // 98304
  float* rQ2   = gh + 98304;                 // 32768

  // --- question path ---
  k_v2<<<1, 256, 0, stream>>>(VQr, WQv_W, WQv_b, v2);
  k_gemm<<<dim3(LQn * Bn / TM, Hn / TN), 256, 0, stream>>>(quesEnc, WQu_W, WQu_b, G1,
                                                           LQn * Bn, Hn, D2H);
  k_sq_rq<<<Bn, 256, 0, stream>>>(G1, v2, Vt1, quesEnc, rQ);
  k_gemm<<<dim3(1, Hn / TN), 256, 0, stream>>>(rQ, Wah_W, Wah_b, u1, Bn, Hn, D2H);

  // --- passage projection (dominant GEMM) ---
  k_gemm<<<dim3(LPn * Bn / TM, Hn / TN), 256, 0, stream>>>(passEnc, WPh_W, WPh_b, passP,
                                                           LPn * Bn, Hn, D2H);

  // --- pointer step 1 ---
  k_sp<<<LPn * Bn / 4, 256, 0, stream>>>(passP, u1, Vt2, sP);
  k_softmax<<<Bn, 256, 0, stream>>>(sP, out);  // aP1 -> out[0 .. 131071]

  // --- ct = sum_p aP1 * passEnc ---
  hipMemsetAsync(ct, 0, Bn * D2H * sizeof(float), stream);
  k_ct<<<dim3(Bn, LPn / 64), 256, 0, stream>>>(out, passEnc, ct);

  // --- GRU cell ---
  k_gemm<<<dim3(1, 1536 / TN), 256, 0, stream>>>(rQ, gru_wih, gru_bih, gi, Bn, 1536, D2H);
  k_gemm<<<dim3(1, 1536 / TN), 256, 0, stream>>>(ct, gru_whh, gru_bhh, gh, Bn, 1536, D2H);
  k_gates<<<Bn * D2H / 256, 256, 0, stream>>>(gi, gh, ct, rQ2);

  // --- pointer step 2 ---
  k_gemm<<<dim3(1, Hn / TN), 256, 0, stream>>>(rQ2, Wah_W, Wah_b, u2, Bn, Hn, D2H);
  k_sp<<<LPn * Bn / 4, 256, 0, stream>>>(passP, u2, Vt2, sP);
  k_softmax<<<Bn, 256, 0, stream>>>(sP, out + Bn * LPn);  // aP2
}

// Round 2
// 906.987 us; speedup vs baseline: 1.1814x; 1.1814x over previous
//
#include <hip/hip_runtime.h>
#include <math.h>

// AnswerPointerNetwork: H=256, B=64, LP=2048, LQ=64, fp32 in/out.
// R2: big GEMMs -> bf16 MFMA (16x16x32), block tile 64 rows x 256 cols (full N),
//     sQ / sP1 reductions fused into GEMM epilogue. A converted fp32->bf16
//     in-register during staging; weights pre-converted once.

constexpr int Bn   = 64;
constexpr int Hn   = 256;
constexpr int D2H  = 512;
constexpr int LPn  = 2048;
constexpr int LQn  = 64;

typedef __attribute__((ext_vector_type(8))) short bf16x8;
typedef __attribute__((ext_vector_type(4))) float f32x4;
typedef __attribute__((ext_vector_type(4))) short short4v;

__device__ inline float waveAllSum(float v) {
  #pragma unroll
  for (int o = 32; o > 0; o >>= 1) v += __shfl_xor(v, o, 64);
  return v;
}
__device__ inline float waveAllMax(float v) {
  #pragma unroll
  for (int o = 32; o > 0; o >>= 1) v = fmaxf(v, __shfl_xor(v, o, 64));
  return v;
}

__device__ inline short f2bf(float f) {
  union { float f; unsigned u; } v; v.f = f;
  unsigned r = v.u + 0x7FFF + ((v.u >> 16) & 1);  // RTNE
  return (short)(r >> 16);
}

// ---------------- weight conversion: WQu_W, WPh_W -> bf16 ----------------
__global__ __launch_bounds__(256) void k_wcvt(const float* __restrict__ WQu,
                                              const float* __restrict__ WPh,
                                              short* __restrict__ wqu16,
                                              short* __restrict__ wph16) {
  int e = (blockIdx.x * 256 + threadIdx.x) * 4;  // 0 .. 262140
  const float* src; short* dst; int off;
  if (e < 131072) { src = WQu; dst = wqu16; off = e; }
  else            { src = WPh; dst = wph16; off = e - 131072; }
  f32x4 f = *(const f32x4*)&src[off];
  short4v h;
  h[0] = f2bf(f[0]); h[1] = f2bf(f[1]); h[2] = f2bf(f[2]); h[3] = f2bf(f[3]);
  *(short4v*)&dst[off] = h;
}

// ---------------- tiny: v2 = VQr @ WQv_W.T + WQv_b ----------------
__global__ __launch_bounds__(256) void k_v2(const float* __restrict__ VQr,
                                            const float* __restrict__ WQv_W,
                                            const float* __restrict__ WQv_b,
                                            float* __restrict__ v2) {
  __shared__ float s[256];
  int t = threadIdx.x;
  s[t] = VQr[t];
  __syncthreads();
  float acc = WQv_b[t];
  for (int k = 0; k < 256; ++k) acc += s[k] * WQv_W[t * 256 + k];
  v2[t] = acc;
}

// ---------------- fused bf16 MFMA GEMM + tanh-dot epilogue ----------------
// C[m][n] = sum_k A[m][k]*W[n][k] + bias[n]   (A fp32, W bf16, K=512, N=256)
// rows m = outer*64 + b (b = m & 63). Block = 64 rows x 256 cols, 4 waves.
// Epilogue: sOut[b*sstride + blockIdx.x] = sum_n tanh(C + u[b*ustride? + n]) * vt[b][n]
__global__ __launch_bounds__(256) void k_mfma_fused(
    const float* __restrict__ A,
    const short* __restrict__ Wb,
    const float* __restrict__ bias,
    const float* __restrict__ u,     // [B][256] if ustride=256, [256] if ustride=0
    const float* __restrict__ vt,    // [B][256]
    float* __restrict__ C,           // [M][256] or nullptr
    float* __restrict__ sOut,        // [B][sstride]
    int ustride, int sstride)
{
  __shared__ __align__(16) short Abuf[64 * 72];   // 64 rows x 64k, pad to 72
  __shared__ __align__(16) short Bbuf[256 * 72];  // 256 n  x 64k, pad to 72
  __shared__ float sred[4][64];

  const int tid  = threadIdx.x;
  const int w    = tid >> 6;
  const int l    = tid & 63;
  const int l15  = l & 15;
  const int quad = l >> 4;
  const long bm  = (long)blockIdx.x * 64;

  f32x4 acc[4][4];
  #pragma unroll
  for (int i = 0; i < 4; ++i)
    #pragma unroll
    for (int j = 0; j < 4; ++j)
      acc[i][j] = (f32x4)0.f;

  for (int k0 = 0; k0 < 512; k0 += 64) {
    // --- stage A tile (fp32 -> bf16): 64 rows x 64 k ---
    {
      const int r  = tid >> 2;
      const int ks = (tid & 3) * 16;
      const f32x4* src = (const f32x4*)&A[(bm + r) * 512 + k0 + ks];
      f32x4 f0 = src[0], f1 = src[1], f2 = src[2], f3 = src[3];
      bf16x8 h0, h1;
      h0[0] = f2bf(f0[0]); h0[1] = f2bf(f0[1]); h0[2] = f2bf(f0[2]); h0[3] = f2bf(f0[3]);
      h0[4] = f2bf(f1[0]); h0[5] = f2bf(f1[1]); h0[6] = f2bf(f1[2]); h0[7] = f2bf(f1[3]);
      h1[0] = f2bf(f2[0]); h1[1] = f2bf(f2[1]); h1[2] = f2bf(f2[2]); h1[3] = f2bf(f2[3]);
      h1[4] = f2bf(f3[0]); h1[5] = f2bf(f3[1]); h1[6] = f2bf(f3[2]); h1[7] = f2bf(f3[3]);
      *(bf16x8*)&Abuf[r * 72 + ks]     = h0;
      *(bf16x8*)&Abuf[r * 72 + ks + 8] = h1;
    }
    // --- stage B tile (already bf16): 256 n x 64 k ---
    #pragma unroll
    for (int q = 0; q < 8; ++q) {
      int n = q * 32 + (tid >> 3);
      int s = tid & 7;
      bf16x8 vsh = *(const bf16x8*)&Wb[n * 512 + k0 + s * 8];
      *(bf16x8*)&Bbuf[n * 72 + s * 8] = vsh;
    }
    __syncthreads();
    #pragma unroll
    for (int h = 0; h < 2; ++h) {
      bf16x8 af[4], bfr[4];
      #pragma unroll
      for (int i = 0; i < 4; ++i)
        af[i] = *(const bf16x8*)&Abuf[(i * 16 + l15) * 72 + h * 32 + quad * 8];
      #pragma unroll
      for (int j = 0; j < 4; ++j)
        bfr[j] = *(const bf16x8*)&Bbuf[(w * 64 + j * 16 + l15) * 72 + h * 32 + quad * 8];
      #pragma unroll
      for (int i = 0; i < 4; ++i)
        #pragma unroll
        for (int j = 0; j < 4; ++j)
          acc[i][j] = __builtin_amdgcn_mfma_f32_16x16x32_bf16(af[i], bfr[j], acc[i][j], 0, 0, 0);
    }
    __syncthreads();
  }

  // --- epilogue: bias add, optional C store, fused tanh-dot reduction ---
  float srow[4][4];
  #pragma unroll
  for (int i = 0; i < 4; ++i) {
    #pragma unroll
    for (int r = 0; r < 4; ++r) {
      const int row = i * 16 + quad * 4 + r;   // == b
      float s_acc = 0.f;
      #pragma unroll
      for (int j = 0; j < 4; ++j) {
        const int n = w * 64 + j * 16 + l15;
        float val = acc[i][j][r] + bias[n];
        if (C) C[(bm + row) * 256 + n] = val;
        float uu = u[ustride * row + n];
        s_acc += tanhf(val + uu) * vt[row * 256 + n];
      }
      srow[i][r] = s_acc;
    }
  }
  #pragma unroll
  for (int off = 1; off < 16; off <<= 1) {
    #pragma unroll
    for (int i = 0; i < 4; ++i)
      #pragma unroll
      for (int r = 0; r < 4; ++r)
        srow[i][r] += __shfl_xor(srow[i][r], off, 64);
  }
  if (l15 == 0) {
    #pragma unroll
    for (int i = 0; i < 4; ++i)
      #pragma unroll
      for (int r = 0; r < 4; ++r)
        sred[w][i * 16 + quad * 4 + r] = srow[i][r];
  }
  __syncthreads();
  if (tid < 64) {
    float s = sred[0][tid] + sred[1][tid] + sred[2][tid] + sred[3][tid];
    sOut[(long)tid * sstride + blockIdx.x] = s;
  }
}

// ---------------- generic fp32 GEMM (small matmuls): C = A @ W^T + bias ----
constexpr int TM = 64, TN = 64, TK = 32;
constexpr int PAD = 4;

__global__ __launch_bounds__(256) void k_gemm(const float* __restrict__ A,
                                              const float* __restrict__ W,
                                              const float* __restrict__ bias,
                                              float* __restrict__ C,
                                              int M, int N, int K) {
  __shared__ float As[TK][TM + PAD];
  __shared__ float Bs[TK][TN + PAD];
  const int bm = blockIdx.x * TM;
  const int bn = blockIdx.y * TN;
  const int tid = threadIdx.x;
  const int tx = tid & 15;
  const int ty = tid >> 4;
  float acc[4][4] = {};

  for (int k0 = 0; k0 < K; k0 += TK) {
    #pragma unroll
    for (int i = 0; i < 2; ++i) {
      int f = tid + 256 * i;
      int m = f >> 3;
      int kq = (f & 7) << 2;
      float4 v = *(const float4*)&A[(size_t)(bm + m) * K + k0 + kq];
      As[kq + 0][m] = v.x; As[kq + 1][m] = v.y; As[kq + 2][m] = v.z; As[kq + 3][m] = v.w;
    }
    #pragma unroll
    for (int i = 0; i < 2; ++i) {
      int f = tid + 256 * i;
      int n = f >> 3;
      int kq = (f & 7) << 2;
      float4 v = *(const float4*)&W[(size_t)(bn + n) * K + k0 + kq];
      Bs[kq + 0][n] = v.x; Bs[kq + 1][n] = v.y; Bs[kq + 2][n] = v.z; Bs[kq + 3][n] = v.w;
    }
    __syncthreads();
    #pragma unroll
    for (int k = 0; k < TK; ++k) {
      float4 a4 = *(const float4*)&As[k][ty * 4];
      float4 b4 = *(const float4*)&Bs[k][tx * 4];
      float aa[4] = {a4.x, a4.y, a4.z, a4.w};
      float bb[4] = {b4.x, b4.y, b4.z, b4.w};
      #pragma unroll
      for (int i = 0; i < 4; ++i)
        #pragma unroll
        for (int j = 0; j < 4; ++j)
          acc[i][j] = fmaf(aa[i], bb[j], acc[i][j]);
    }
    __syncthreads();
  }

  float4 bset = *(const float4*)&bias[bn + tx * 4];
  #pragma unroll
  for (int i = 0; i < 4; ++i) {
    int m = bm + ty * 4 + i;
    float4 v;
    v.x = acc[i][0] + bset.x;
    v.y = acc[i][1] + bset.y;
    v.z = acc[i][2] + bset.z;
    v.w = acc[i][3] + bset.w;
    *(float4*)&C[(size_t)m * N + bn + tx * 4] = v;
  }
}

// ---------------- softmax(sQ) + rQ accumulation, one block per b ----------
__global__ __launch_bounds__(256) void k_softmax_rq(const float* __restrict__ sQ,
                                                    const float* __restrict__ quesEnc,
                                                    float* __restrict__ rQ) {
  int b = blockIdx.x, tid = threadIdx.x;
  __shared__ float s_a[LQn];
  if (tid < 64) {
    float s = sQ[b * LQn + tid];
    float m = waveAllMax(s);
    float e = expf(s - m);
    float sum = waveAllSum(e);
    s_a[tid] = e / sum;
  }
  __syncthreads();
  #pragma unroll
  for (int rep = 0; rep < 2; ++rep) {
    int d = tid + rep * 256;
    float acc = 0.f;
    for (int q = 0; q < LQn; ++q)
      acc += s_a[q] * quesEnc[(size_t)(q * Bn + b) * D2H + d];
    rQ[b * D2H + d] = acc;
  }
}

// ---------------- sP[b][p] = sum_h tanh(passP[p,b,h]+u[b,h])*Vt2[b,h] ------
__global__ __launch_bounds__(256) void k_sp(const float* __restrict__ passP,
                                            const float* __restrict__ u,
                                            const float* __restrict__ Vt2,
                                            float* __restrict__ sP) {
  int flat = blockIdx.x * 4 + (threadIdx.x >> 6);
  int lane = threadIdx.x & 63;
  int b = flat & (Bn - 1);
  int p = flat >> 6;
  float4 v  = *(const float4*)&passP[(size_t)flat * Hn + lane * 4];
  float4 uu = *(const float4*)&u[b * Hn + lane * 4];
  float4 vt = *(const float4*)&Vt2[b * Hn + lane * 4];
  float s = tanhf(v.x + uu.x) * vt.x + tanhf(v.y + uu.y) * vt.y +
            tanhf(v.z + uu.z) * vt.z + tanhf(v.w + uu.w) * vt.w;
  s = waveAllSum(s);
  if (lane == 0) sP[b * LPn + p] = s;
}

// ---------------- softmax over 2048, one block per b ----------------
__global__ __launch_bounds__(256) void k_softmax(const float* __restrict__ sP,
                                                 float* __restrict__ out) {
  int b = blockIdx.x, tid = threadIdx.x;
  int lane = tid & 63, wid = tid >> 6;
  __shared__ float red[4];
  float v[8];
  float m = -1e30f;
  #pragma unroll
  for (int i = 0; i < 8; ++i) {
    v[i] = sP[b * LPn + i * 256 + tid];
    m = fmaxf(m, v[i]);
  }
  m = waveAllMax(m);
  if (lane == 0) red[wid] = m;
  __syncthreads();
  m = fmaxf(fmaxf(red[0], red[1]), fmaxf(red[2], red[3]));
  float s = 0.f;
  #pragma unroll
  for (int i = 0; i < 8; ++i) { v[i] = expf(v[i] - m); s += v[i]; }
  s = waveAllSum(s);
  __syncthreads();
  if (lane == 0) red[wid] = s;
  __syncthreads();
  s = red[0] + red[1] + red[2] + red[3];
  float inv = 1.0f / s;
  #pragma unroll
  for (int i = 0; i < 8; ++i) out[b * LPn + i * 256 + tid] = v[i] * inv;
}

// ---------------- ct[b][d] = sum_p aP[b][p]*passEnc[p,b,d] ----------------
__global__ __launch_bounds__(256) void k_ct(const float* __restrict__ aP,
                                            const float* __restrict__ passEnc,
                                            float* __restrict__ ct) {
  int b = blockIdx.x;
  int p0 = blockIdx.y * 64;
  int tid = threadIdx.x;
  float acc0 = 0.f, acc1 = 0.f;
  for (int pp = 0; pp < 64; ++pp) {
    int p = p0 + pp;
    float a = aP[b * LPn + p];
    const float* row = &passEnc[(size_t)(p * Bn + b) * D2H];
    acc0 += a * row[tid];
    acc1 += a * row[tid + 256];
  }
  atomicAdd(&ct[b * D2H + tid], acc0);
  atomicAdd(&ct[b * D2H + tid + 256], acc1);
}

// ---------------- GRU gates ----------------
__global__ __launch_bounds__(256) void k_gates(const float* __restrict__ gi,
                                               const float* __restrict__ gh,
                                               const float* __restrict__ ct,
                                               float* __restrict__ rQ2) {
  int idx = blockIdx.x * 256 + threadIdx.x;
  int b = idx >> 9;
  int j = idx & 511;
  const float* gib = gi + b * 1536;
  const float* ghb = gh + b * 1536;
  float r = 1.f / (1.f + expf(-(gib[j] + ghb[j])));
  float z = 1.f / (1.f + expf(-(gib[512 + j] + ghb[512 + j])));
  float n = tanhf(gib[1024 + j] + r * ghb[1024 + j]);
  rQ2[b * D2H + j] = (1.f - z) * n + z * ct[b * D2H + j];
}

extern "C" void kernel_launch(void* const* d_in, const int* in_sizes, int n_in,
                              void* d_out, int out_size, void* d_ws, size_t ws_size,
                              hipStream_t stream) {
  const float* passEnc  = (const float*)d_in[0];
  const float* quesEnc  = (const float*)d_in[1];
  const float* WQu_W    = (const float*)d_in[2];
  const float* WQu_b    = (const float*)d_in[3];
  const float* WQv_W    = (const float*)d_in[4];
  const float* WQv_b    = (const float*)d_in[5];
  const float* WPh_W    = (const float*)d_in[6];
  const float* WPh_b    = (const float*)d_in[7];
  const float* Wah_W    = (const float*)d_in[8];
  const float* Wah_b    = (const float*)d_in[9];
  const float* Vt1      = (const float*)d_in[10];
  const float* Vt2      = (const float*)d_in[11];
  const float* VQr      = (const float*)d_in[12];
  const float* gru_wih  = (const float*)d_in[13];
  const float* gru_whh  = (const float*)d_in[14];
  const float* gru_bih  = (const float*)d_in[15];
  const float* gru_bhh  = (const float*)d_in[16];
  float* out = (float*)d_out;

  // workspace layout (floats)
  float* ws = (float*)d_ws;
  float* passP = ws;                         // 33554432
  float* v2    = ws + 33554432;              // 256
  float* rQ    = v2 + 256;                   // 32768
  float* u1    = rQ + 32768;                 // 16384
  float* u2    = u1 + 16384;                 // 16384
  float* sP    = u2 + 16384;                 // 131072
  float* ct    = sP + 131072;                // 32768
  float* gi    = ct + 32768;                 // 98304
  float* gh    = gi + 98304;                 // 98304
  float* rQ2   = gh + 98304;                 // 32768
  float* sQ    = rQ2 + 32768;                // 4096
  short* wqu16 = (short*)(sQ + 4096);        // 131072 shorts
  short* wph16 = wqu16 + 131072;             // 131072 shorts

  // --- weight conversion (0.5 MB, once per call) ---
  k_wcvt<<<256, 256, 0, stream>>>(WQu_W, WPh_W, wqu16, wph16);

  // --- question path: v2, fused G1-GEMM + sQ, softmax + rQ, u1 ---
  k_v2<<<1, 256, 0, stream>>>(VQr, WQv_W, WQv_b, v2);
  k_mfma_fused<<<LQn, 256, 0, stream>>>(quesEnc, wqu16, WQu_b, v2, Vt1,
                                        nullptr, sQ, 0, LQn);
  k_softmax_rq<<<Bn, 256, 0, stream>>>(sQ, quesEnc, rQ);
  k_gemm<<<dim3(1, Hn / TN), 256, 0, stream>>>(rQ, Wah_W, Wah_b, u1, Bn, Hn, D2H);

  // --- passage: fused passP-GEMM + sP1 epilogue ---
  k_mfma_fused<<<LPn, 256, 0, stream>>>(passEnc, wph16, WPh_b, u1, Vt2,
                                        passP, sP, Hn, LPn);
  k_softmax<<<Bn, 256, 0, stream>>>(sP, out);  // aP1

  // --- ct = sum_p aP1 * passEnc ---
  hipMemsetAsync(ct, 0, Bn * D2H * sizeof(float), stream);
  k_ct<<<dim3(Bn, LPn / 64), 256, 0, stream>>>(out, passEnc, ct);

  // --- GRU cell ---
  k_gemm<<<dim3(1, 1536 / TN), 256, 0, stream>>>(rQ, gru_wih, gru_bih, gi, Bn, 1536, D2H);
  k_gemm<<<dim3(1, 1536 / TN), 256, 0, stream>>>(ct, gru_whh, gru_bhh, gh, Bn, 1536, D2H);
  k_gates<<<Bn * D2H / 256, 256, 0, stream>>>(gi, gh, ct, rQ2);

  // --- pointer step 2 ---
  k_gemm<<<dim3(1, Hn / TN), 256, 0, stream>>>(rQ2, Wah_W, Wah_b, u2, Bn, Hn, D2H);
  k_sp<<<LPn * Bn / 4, 256, 0, stream>>>(passP, u2, Vt2, sP);
  k_softmax<<<Bn, 256, 0, stream>>>(sP, out + Bn * LPn);  // aP2
}